// Round 9
// baseline (105.014 us; speedup 1.0000x reference)
//
#include <hip/hip_runtime.h>
#include <hip/hip_bf16.h>

// Conv2d 3x3 s1 p1, NCHW: X(32,128,56,56) f32 * W(256,128,3,3) f32 -> out(32,256,56,56) f32
// R9: latency decoupling (R8 was null; nothing saturated at 8 waves/CU => latency-bound).
//  (1) Cross-tap B-prefetch: bPf[2][7] (static tap&1); tap t issues tap t+1's 7
//      ds_read_b128, MFMAs run on previous buffer => lgkm latency hidden under MFMA.
//  (2) A triple-buffer aReg[3], static tap%3 (tap8 cross-slice prefetch -> slot 0 =
//      tap0's read slot, no collision; all indices compile-time).
//  (3) vmcnt FIFO fix: stageWin(icb+1) issued at END of tap 4 (not slice start), so
//      per-tap A-prefetch global loads are NOT queued behind the HBM staging burst
//      (vmcnt retires in issue order - waiting on a young load forces old ones).
// Sync structure unchanged from R7/R8 (passing): window dbuf, vmcnt(0)+barrier+
// sched_barrier once per slice; weights L2->VGPR.

#define IC 128
#define OC 256
#define HH 56
#define WW 56
#define NB 32
#define PH 58
#define PW 58
#define PS (PH*PW)
#define NPIX (HH*WW)      // 3136
#define GPIX (NB*NPIX)    // 100352
#define KDIM (IC*9)       // 1152

#define BMH 128           // oc per block
#define BNP 448           // pixels per block (8 rows x 56)

#define WINB 40960        // one window buffer: [10 rows][64 cols][32 ic] bf16

typedef short  bf16x8 __attribute__((ext_vector_type(8)));
typedef float  f32x4  __attribute__((ext_vector_type(4)));
typedef unsigned int u32;

__device__ __forceinline__ unsigned short f2bf(float f) {
  union { float f; unsigned int u; } c; c.f = f;
  unsigned int u = c.u;
  u += 0x7FFFu + ((u >> 16) & 1u);
  return (unsigned short)(u >> 16);
}

__device__ __forceinline__ void gload16(const unsigned short* g, unsigned short* l) {
  __builtin_amdgcn_global_load_lds(
      (const __attribute__((address_space(1))) u32*)g,
      (__attribute__((address_space(3))) u32*)l, 16, 0, 0);
}

// involution on bytes: bits 4-7 ^= bits 8-11
__device__ __forceinline__ int swz(int a) { return a ^ (((a >> 8) & 15) << 4); }

// ---- prepass 1a: zero padded border of Xt
__global__ __launch_bounds__(256) void zero_border(unsigned short* __restrict__ Xt, int total) {
  int idx = blockIdx.x * 256 + threadIdx.x;
  if (idx >= total) return;
  int e  = idx & 127;
  int b  = idx >> 7;
  int n  = b / 228;
  int bp = b - n * 228;
  int y, x;
  if (bp < 58)       { y = 0;  x = bp; }
  else if (bp < 116) { y = 57; x = bp - 58; }
  else {
    int b2 = bp - 116;
    y = 1 + (b2 >> 1);
    x = (b2 & 1) * 57;
  }
  Xt[((long)(n * PH + y) * PW + x) * IC + e] = 0;
}

// ---- prepass 1b: NCHW f32 -> NHWC-padded bf16 (LDS-tiled transpose)
__global__ __launch_bounds__(256) void pad_x_nhwc(const float* __restrict__ X,
                                                  unsigned short* __restrict__ Xt) {
  __shared__ float tile[128][65];
  const int t   = threadIdx.x;
  const int p0  = blockIdx.x * 64;
  const int n   = p0 / NPIX;
  const int rem = p0 - n * NPIX;

  const int pixl = t & 63;
  const int q    = t >> 6;
  const float* src = X + ((long)n * IC + q) * NPIX + rem + pixl;
  #pragma unroll
  for (int i = 0; i < 32; ++i)
    tile[q + i * 4][pixl] = src[(long)i * 4 * NPIX];
  __syncthreads();

  const int pix = t >> 2;
  const int icq = (t & 3) * 32;
  int p = rem + pix;
  int y = p / WW, x = p - y * WW;
  unsigned short* dst = Xt + ((long)(n * PH + y + 1) * PW + (x + 1)) * IC + icq;
  #pragma unroll
  for (int g = 0; g < 4; ++g) {
    bf16x8 v;
    #pragma unroll
    for (int j = 0; j < 8; ++j)
      ((unsigned short*)&v)[j] = f2bf(tile[icq + g * 8 + j][pix]);
    *reinterpret_cast<bf16x8*>(dst + g * 8) = v;
  }
}

// ---- prepass 2: W (OIHW f32) -> Wb bf16 [tap][ic_octet s][oc][8 ic]
__global__ __launch_bounds__(256) void pack_w(const float* __restrict__ W,
                                              unsigned short* __restrict__ Wb, int total) {
  int idx = blockIdx.x * 256 + threadIdx.x;
  if (idx >= total) return;
  int e  = idx & 7;
  int oc = (idx >> 3) & 255;
  int s  = (idx >> 11) & 15;
  int t  = idx >> 15;
  Wb[idx] = f2bf(W[(oc * IC + s * 8 + e) * 9 + t]);
}

// ---- main: halo-window implicit GEMM, register-pipelined taps
__global__ __launch_bounds__(512) void conv_win(
    const unsigned short* __restrict__ Xt,
    const unsigned short* __restrict__ Wb,
    float* __restrict__ out) {
  __shared__ __align__(16) unsigned short lds[40960];   // 80 KB: 2 window buffers
  char* const ldsb = (char*)lds;

  const int tid  = threadIdx.x;
  const int lane = tid & 63;
  const int w    = tid >> 6;
  const int wm = w >> 2, wn = w & 3;     // 2M x 4N wave grid; wave tile 64oc x 112pix
  const int l15 = lane & 15, lh = lane >> 4;

  // XCD-aware bijective remap: 448 = 8 x 56
  const int bid   = blockIdx.x;
  const int wg    = (bid & 7) * 56 + (bid >> 3);
  const int ntile = wg >> 1;             // 0..223
  const int mhalf = wg & 1;
  const int n   = ntile / 7;
  const int rg  = ntile - n * 7;
  const int y0  = rg * 8;                // padded top row of window
  const int ocb = mhalf * BMH;

  // ---- A source: per-lane VGPR loads, coalesced (16 lanes x 16B contiguous)
  // elem offset(tap, icb, m): tap*32768 + icb*8192 + m*128 (+ lh*2048 + row*8 in base)
  const unsigned short* aBase = Wb + (size_t)lh * 2048 + (ocb + wm * 64 + l15) * 8;

  // ---- window staging sources (5 slots/thread; layout [10 rows][64 cols][32ic])
  const unsigned short* srcW[5];
  #pragma unroll
  for (int r = 0; r < 5; ++r) {
    int xw   = swz((tid + r * 512) * 16);
    int slab = xw >> 6;                  // row*64 + col
    int rr   = slab >> 6;
    int cc   = slab & 63; if (cc > 57) cc = 57;     // pad cols 58-63: dup (never read)
    srcW[r] = Xt + ((long)((n * PH + y0 + rr) * PW + cc)) * IC + ((xw & 63) >> 1);
  }

  // ---- fragment linear offsets (window)
  int pixLin[7];
  #pragma unroll
  for (int j = 0; j < 7; ++j) {
    int local = wn * 112 + j * 16 + l15;     // 0..447 within block
    int wy = local / 56, wx = local - wy * 56;
    pixLin[j] = ((wy * 64 + wx) << 6) + lh * 16;
  }

  f32x4 acc[4][7];
  #pragma unroll
  for (int m = 0; m < 4; ++m)
    #pragma unroll
    for (int j = 0; j < 7; ++j)
      acc[m][j] = (f32x4){0.f, 0.f, 0.f, 0.f};

  auto stageWin = [&](int icb) {          // slice icb -> buf (icb&1); wave-uniform dest
    char* base = ldsb + (icb & 1) * WINB + (tid & ~63) * 16;
    #pragma unroll
    for (int r = 0; r < 5; ++r)
      gload16(srcW[r] + icb * 32, (unsigned short*)(base + r * 8192));
  };

  // ---- prologue
  stageWin(0);
  bf16x8 aReg[3][4];                      // all indices compile-time (tap unrolled)
  #pragma unroll
  for (int m = 0; m < 4; ++m)
    aReg[0][m] = *(const bf16x8*)(aBase + m * 128);        // A(icb0, tap0)
  asm volatile("s_waitcnt vmcnt(0)" ::: "memory");
  __builtin_amdgcn_s_barrier();
  __builtin_amdgcn_sched_barrier(0);

  bf16x8 bPf[2][7];                       // B-frag double buffer, static tap&1 index

  for (int icb = 0; icb < 4; ++icb) {
    const int winSel = (icb & 1) * WINB;

    // slice prologue: tap0 B-frags (window only certified at the barrier)
    #pragma unroll
    for (int j = 0; j < 7; ++j)
      bPf[0][j] = *(const bf16x8*)(ldsb + winSel + swz(pixLin[j]));

    #pragma unroll
    for (int tap = 0; tap < 9; ++tap) {
      // A prefetch for next tap -> slot (tap+1)%3 (compile-time)
      if (tap < 8) {
        #pragma unroll
        for (int m = 0; m < 4; ++m)
          aReg[(tap + 1) % 3][m] = *(const bf16x8*)(aBase + (size_t)(tap + 1) * 32768
                                                          + (size_t)icb * 8192 + m * 128);
      } else if (icb < 3) {
        #pragma unroll
        for (int m = 0; m < 4; ++m)
          aReg[0][m] = *(const bf16x8*)(aBase + (size_t)(icb + 1) * 8192 + m * 128);
      }

      // B prefetch for next tap -> buffer (tap+1)&1 (compile-time)
      if (tap < 8) {
        const int nt = tap + 1;
        const int ndy = nt / 3, ndx = nt - ndy * 3;
        const int ntoff = ((ndy * 64 + ndx) << 6);
        #pragma unroll
        for (int j = 0; j < 7; ++j)
          bPf[(tap + 1) & 1][j] = *(const bf16x8*)(ldsb + winSel + swz(pixLin[j] + ntoff));
      }

      // MFMAs on current buffers (previous tap's prefetches)
      __builtin_amdgcn_s_setprio(1);
      #pragma unroll
      for (int j = 0; j < 7; ++j)
        #pragma unroll
        for (int m = 0; m < 4; ++m)
          acc[m][j] = __builtin_amdgcn_mfma_f32_16x16x32_bf16(aReg[tap % 3][m],
                                                              bPf[tap & 1][j],
                                                              acc[m][j], 0, 0, 0);
      __builtin_amdgcn_s_setprio(0);

      // vmcnt-FIFO-aware staging placement: issue AFTER tap 4's MFMAs so that
      // A(t<=5) prefetches are older than staging (no false waits) and staging
      // has ~4 taps to complete before the end-of-slice vmcnt(0).
      if (tap == 4 && icb < 3) stageWin(icb + 1);
    }

    // window(icb+1) fully staged (all waves) before reading it; WAR on buf icb&1
    // certified for the stage at icb+2 by this same barrier.
    asm volatile("s_waitcnt vmcnt(0)" ::: "memory");
    __builtin_amdgcn_s_barrier();
    __builtin_amdgcn_sched_barrier(0);
  }

  // ---- epilogue: D row=(lane>>4)*4+reg (oc), col=lane&15 (pixel)
  #pragma unroll
  for (int j = 0; j < 7; ++j) {
    int local = wn * 112 + j * 16 + l15;
    int pidx  = rg * BNP + local;                 // pixel within image
    #pragma unroll
    for (int m = 0; m < 4; ++m) {
      int oc = ocb + wm * 64 + m * 16 + lh * 4;
      float* op = out + ((long)(n * OC + oc)) * NPIX + pidx;
      #pragma unroll
      for (int r = 0; r < 4; ++r)
        op[(long)r * NPIX] = acc[m][j][r];
    }
  }
}

// ---- fallback: naive direct conv fp32
__global__ __launch_bounds__(256) void conv_naive(const float* __restrict__ X,
                                                  const float* __restrict__ W,
                                                  float* __restrict__ out, int total) {
  int idx = blockIdx.x * 256 + threadIdx.x;
  if (idx >= total) return;
  int prow = idx % NPIX;
  int t    = idx / NPIX;
  int oc   = t % OC;
  int n    = t / OC;
  int oh = prow / WW, ow = prow % WW;
  float s = 0.f;
  for (int ic = 0; ic < IC; ++ic) {
    const float* xp = X + ((long)(n * IC + ic)) * NPIX;
    const float* wp = W + ((long)(oc * IC + ic)) * 9;
    #pragma unroll
    for (int kh = 0; kh < 3; ++kh) {
      int ih = oh + kh - 1;
      if (ih < 0 || ih >= HH) continue;
      #pragma unroll
      for (int kw = 0; kw < 3; ++kw) {
        int iw = ow + kw - 1;
        if (iw < 0 || iw >= WW) continue;
        s += xp[ih * WW + iw] * wp[kh * 3 + kw];
      }
    }
  }
  out[idx] = s;
}

extern "C" void kernel_launch(void* const* d_in, const int* in_sizes, int n_in,
                              void* d_out, int out_size, void* d_ws, size_t ws_size,
                              hipStream_t stream) {
  const float* X = (const float*)d_in[0];
  const float* W = (const float*)d_in[1];
  float* out = (float*)d_out;

  const size_t xt_elems = (size_t)NB * PS * IC;
  const size_t wb_elems = (size_t)9 * 16 * 256 * 8;   // 294,912
  const size_t need = (xt_elems + wb_elems) * sizeof(unsigned short);

  if (ws_size >= need) {
    unsigned short* Xt = (unsigned short*)d_ws;
    unsigned short* Wb = Xt + xt_elems;

    int totB = NB * 228 * IC;
    zero_border<<<(totB + 255) / 256, 256, 0, stream>>>(Xt, totB);
    pad_x_nhwc<<<GPIX / 64, 256, 0, stream>>>(X, Xt);
    int totW = (int)wb_elems;
    pack_w<<<(totW + 255) / 256, 256, 0, stream>>>(W, Wb, totW);
    conv_win<<<(GPIX / BNP) * (OC / BMH), 512, 0, stream>>>(Xt, Wb, out);
  } else {
    int tot = NB * OC * NPIX;
    conv_naive<<<(tot + 255) / 256, 256, 0, stream>>>(X, W, out, tot);
  }
}

// Round 10
// 85.240 us; speedup vs baseline: 1.2320x; 1.2320x over previous
//
#include <hip/hip_runtime.h>
#include <hip/hip_bf16.h>

// Conv2d 3x3 s1 p1, NCHW: X(32,128,56,56) f32 * W(256,128,3,3) f32 -> out(32,256,56,56) f32
// R10 = R8 body (70us, passing) + two register-neutral occupancy/latency fixes:
//  (1) window stride 64->58: buffer 37120B+slack = 37888B, total LDS 75776B < 80KB
//      => 2 blocks/CU (4 waves/SIMD) instead of 1 (2 waves/SIMD). TLP doubles.
//  (2) stageWin(icb+1) issued at END of tap 4 (R9's FIFO fix, 0 extra regs):
//      A-prefetch vmcnt waits at taps<=5 no longer force-retire the staging burst.
// Everything else identical to R8: weights L2->VGPR double-buffered by global tap
// parity, window dbuf + vmcnt(0)+barrier+sched_barrier once per slice, swz reads.

#define IC 128
#define OC 256
#define HH 56
#define WW 56
#define NB 32
#define PH 58
#define PW 58
#define PS (PH*PW)
#define NPIX (HH*WW)      // 3136
#define GPIX (NB*NPIX)    // 100352
#define KDIM (IC*9)       // 1152

#define BMH 128           // oc per block
#define BNP 448           // pixels per block (8 rows x 56)

#define WROWB 3712        // window row stride bytes: 58 cols x 64B
#define WINREAL 37120     // 10 rows x 3712
#define WINB 37888        // buffer size incl. 48-slot staging slack (16B slots: 2368)

typedef short  bf16x8 __attribute__((ext_vector_type(8)));
typedef float  f32x4  __attribute__((ext_vector_type(4)));
typedef unsigned int u32;

__device__ __forceinline__ unsigned short f2bf(float f) {
  union { float f; unsigned int u; } c; c.f = f;
  unsigned int u = c.u;
  u += 0x7FFFu + ((u >> 16) & 1u);
  return (unsigned short)(u >> 16);
}

__device__ __forceinline__ void gload16(const unsigned short* g, unsigned short* l) {
  __builtin_amdgcn_global_load_lds(
      (const __attribute__((address_space(1))) u32*)g,
      (__attribute__((address_space(3))) u32*)l, 16, 0, 0);
}

// involution on bytes: bits 4-7 ^= bits 8-11
__device__ __forceinline__ int swz(int a) { return a ^ (((a >> 8) & 15) << 4); }

// ---- prepass 1a: zero padded border of Xt
__global__ __launch_bounds__(256) void zero_border(unsigned short* __restrict__ Xt, int total) {
  int idx = blockIdx.x * 256 + threadIdx.x;
  if (idx >= total) return;
  int e  = idx & 127;
  int b  = idx >> 7;
  int n  = b / 228;
  int bp = b - n * 228;
  int y, x;
  if (bp < 58)       { y = 0;  x = bp; }
  else if (bp < 116) { y = 57; x = bp - 58; }
  else {
    int b2 = bp - 116;
    y = 1 + (b2 >> 1);
    x = (b2 & 1) * 57;
  }
  Xt[((long)(n * PH + y) * PW + x) * IC + e] = 0;
}

// ---- prepass 1b: NCHW f32 -> NHWC-padded bf16 (LDS-tiled transpose)
__global__ __launch_bounds__(256) void pad_x_nhwc(const float* __restrict__ X,
                                                  unsigned short* __restrict__ Xt) {
  __shared__ float tile[128][65];
  const int t   = threadIdx.x;
  const int p0  = blockIdx.x * 64;
  const int n   = p0 / NPIX;
  const int rem = p0 - n * NPIX;

  const int pixl = t & 63;
  const int q    = t >> 6;
  const float* src = X + ((long)n * IC + q) * NPIX + rem + pixl;
  #pragma unroll
  for (int i = 0; i < 32; ++i)
    tile[q + i * 4][pixl] = src[(long)i * 4 * NPIX];
  __syncthreads();

  const int pix = t >> 2;
  const int icq = (t & 3) * 32;
  int p = rem + pix;
  int y = p / WW, x = p - y * WW;
  unsigned short* dst = Xt + ((long)(n * PH + y + 1) * PW + (x + 1)) * IC + icq;
  #pragma unroll
  for (int g = 0; g < 4; ++g) {
    bf16x8 v;
    #pragma unroll
    for (int j = 0; j < 8; ++j)
      ((unsigned short*)&v)[j] = f2bf(tile[icq + g * 8 + j][pix]);
    *reinterpret_cast<bf16x8*>(dst + g * 8) = v;
  }
}

// ---- prepass 2: W (OIHW f32) -> Wb bf16 [tap][ic_octet s][oc][8 ic]
__global__ __launch_bounds__(256) void pack_w(const float* __restrict__ W,
                                              unsigned short* __restrict__ Wb, int total) {
  int idx = blockIdx.x * 256 + threadIdx.x;
  if (idx >= total) return;
  int e  = idx & 7;
  int oc = (idx >> 3) & 255;
  int s  = (idx >> 11) & 15;
  int t  = idx >> 15;
  Wb[idx] = f2bf(W[(oc * IC + s * 8 + e) * 9 + t]);
}

// ---- main: halo-window implicit GEMM
__global__ __launch_bounds__(512) void conv_win(
    const unsigned short* __restrict__ Xt,
    const unsigned short* __restrict__ Wb,
    float* __restrict__ out) {
  __shared__ __align__(16) unsigned short lds[37888];   // 75776 B: 2 window buffers
  char* const ldsb = (char*)lds;

  const int tid  = threadIdx.x;
  const int lane = tid & 63;
  const int w    = tid >> 6;
  const int wm = w >> 2, wn = w & 3;     // 2M x 4N wave grid; wave tile 64oc x 112pix
  const int l15 = lane & 15, lh = lane >> 4;

  // XCD-aware bijective remap: 448 = 8 x 56
  const int bid   = blockIdx.x;
  const int wg    = (bid & 7) * 56 + (bid >> 3);
  const int ntile = wg >> 1;             // 0..223
  const int mhalf = wg & 1;
  const int n   = ntile / 7;
  const int rg  = ntile - n * 7;
  const int y0  = rg * 8;                // padded top row of window
  const int ocb = mhalf * BMH;

  // ---- A source: per-lane VGPR loads, coalesced (16 lanes x 16B contiguous)
  const unsigned short* aBase = Wb + (size_t)lh * 2048 + (ocb + wm * 64 + l15) * 8;

  // ---- window staging sources (5 slots/thread; content layout [10][58 cols][64B])
  const unsigned short* srcW[5];
  #pragma unroll
  for (int r = 0; r < 5; ++r) {
    int xw = swz((tid + r * 512) * 16);
    if (xw >= WINREAL) xw = WINREAL - 16;          // slack slots: dup last (never read)
    int row = xw / WROWB;
    int rem = xw - row * WROWB;
    int col = rem >> 6;
    srcW[r] = Xt + ((long)((n * PH + y0 + row) * PW + col)) * IC + ((rem & 63) >> 1);
  }

  // ---- fragment linear offsets (window, stride-58 rows)
  int pixLin[7];
  #pragma unroll
  for (int j = 0; j < 7; ++j) {
    int local = wn * 112 + j * 16 + l15;     // 0..447 within block
    int wy = local / 56, wx = local - wy * 56;
    pixLin[j] = (wy * 58 + wx) * 64 + lh * 16;
  }

  f32x4 acc[4][7];
  #pragma unroll
  for (int m = 0; m < 4; ++m)
    #pragma unroll
    for (int j = 0; j < 7; ++j)
      acc[m][j] = (f32x4){0.f, 0.f, 0.f, 0.f};

  auto stageWin = [&](int icb) {          // slice icb -> buf (icb&1); wave-uniform dest
    char* base = ldsb + (icb & 1) * WINB + (tid & ~63) * 16;
    #pragma unroll
    for (int r = 0; r < 5; ++r)
      if (r < 4 || w <= 4)                // call 4: waves 5-7 skip (slots beyond slack)
        gload16(srcW[r] + icb * 32, (unsigned short*)(base + r * 8192));
  };

  // ---- prologue
  stageWin(0);
  bf16x8 aReg[2][4];
  #pragma unroll
  for (int m = 0; m < 4; ++m)
    aReg[0][m] = *(const bf16x8*)(aBase + m * 128);        // A(q=0): tap0, icb0
  asm volatile("s_waitcnt vmcnt(0)" ::: "memory");
  __builtin_amdgcn_s_barrier();
  __builtin_amdgcn_sched_barrier(0);

  for (int icb = 0; icb < 4; ++icb) {
    const int winSel = (icb & 1) * WINB;

    #pragma unroll
    for (int tap = 0; tap < 9; ++tap) {
      // global tap parity: q = icb*9+tap ; 9 odd => q&1 == (icb+tap)&1
      const int rs = (icb + tap) & 1;          // read slot
      const int ps = rs ^ 1;                   // prefetch slot (q+1)

      // prefetch A for q+1 (never collides: ps != rs)
      if (tap < 8) {
        #pragma unroll
        for (int m = 0; m < 4; ++m)
          aReg[ps][m] = *(const bf16x8*)(aBase + (size_t)(tap + 1) * 32768
                                               + (size_t)icb * 8192 + m * 128);
      } else if (icb < 3) {
        #pragma unroll
        for (int m = 0; m < 4; ++m)
          aReg[ps][m] = *(const bf16x8*)(aBase + (size_t)(icb + 1) * 8192 + m * 128);
      }

      const int dy = tap / 3, dx = tap - dy * 3;   // compile-time (tap unrolled)
      const int toff = (dy * 58 + dx) * 64;

      bf16x8 bfv[7];
      #pragma unroll
      for (int j = 0; j < 7; ++j)
        bfv[j] = *(const bf16x8*)(ldsb + winSel + swz(pixLin[j] + toff));

      __builtin_amdgcn_s_setprio(1);
      #pragma unroll
      for (int j = 0; j < 7; ++j)
        #pragma unroll
        for (int m = 0; m < 4; ++m)
          acc[m][j] = __builtin_amdgcn_mfma_f32_16x16x32_bf16(aReg[rs][m], bfv[j],
                                                              acc[m][j], 0, 0, 0);
      __builtin_amdgcn_s_setprio(0);

      // FIFO-aware staging: issue after tap 4 so A-prefetch waits at taps<=5 do not
      // force-retire the staging burst (vmcnt retires oldest-first).
      if (tap == 4 && icb < 3) stageWin(icb + 1);
    }

    // window(icb+1) fully staged (all waves) before reading it; WAR on buf icb&1
    // certified for the stage at icb+2 by this same barrier.
    asm volatile("s_waitcnt vmcnt(0)" ::: "memory");
    __builtin_amdgcn_s_barrier();
    __builtin_amdgcn_sched_barrier(0);
  }

  // ---- epilogue: D row=(lane>>4)*4+reg (oc), col=lane&15 (pixel)
  #pragma unroll
  for (int j = 0; j < 7; ++j) {
    int local = wn * 112 + j * 16 + l15;
    int pidx  = rg * BNP + local;                 // pixel within image
    #pragma unroll
    for (int m = 0; m < 4; ++m) {
      int oc = ocb + wm * 64 + m * 16 + lh * 4;
      float* op = out + ((long)(n * OC + oc)) * NPIX + pidx;
      #pragma unroll
      for (int r = 0; r < 4; ++r)
        op[(long)r * NPIX] = acc[m][j][r];
    }
  }
}

// ---- fallback: naive direct conv fp32
__global__ __launch_bounds__(256) void conv_naive(const float* __restrict__ X,
                                                  const float* __restrict__ W,
                                                  float* __restrict__ out, int total) {
  int idx = blockIdx.x * 256 + threadIdx.x;
  if (idx >= total) return;
  int prow = idx % NPIX;
  int t    = idx / NPIX;
  int oc   = t % OC;
  int n    = t / OC;
  int oh = prow / WW, ow = prow % WW;
  float s = 0.f;
  for (int ic = 0; ic < IC; ++ic) {
    const float* xp = X + ((long)(n * IC + ic)) * NPIX;
    const float* wp = W + ((long)(oc * IC + ic)) * 9;
    #pragma unroll
    for (int kh = 0; kh < 3; ++kh) {
      int ih = oh + kh - 1;
      if (ih < 0 || ih >= HH) continue;
      #pragma unroll
      for (int kw = 0; kw < 3; ++kw) {
        int iw = ow + kw - 1;
        if (iw < 0 || iw >= WW) continue;
        s += xp[ih * WW + iw] * wp[kh * 3 + kw];
      }
    }
  }
  out[idx] = s;
}

extern "C" void kernel_launch(void* const* d_in, const int* in_sizes, int n_in,
                              void* d_out, int out_size, void* d_ws, size_t ws_size,
                              hipStream_t stream) {
  const float* X = (const float*)d_in[0];
  const float* W = (const float*)d_in[1];
  float* out = (float*)d_out;

  const size_t xt_elems = (size_t)NB * PS * IC;
  const size_t wb_elems = (size_t)9 * 16 * 256 * 8;   // 294,912
  const size_t need = (xt_elems + wb_elems) * sizeof(unsigned short);

  if (ws_size >= need) {
    unsigned short* Xt = (unsigned short*)d_ws;
    unsigned short* Wb = Xt + xt_elems;

    int totB = NB * 228 * IC;
    zero_border<<<(totB + 255) / 256, 256, 0, stream>>>(Xt, totB);
    pad_x_nhwc<<<GPIX / 64, 256, 0, stream>>>(X, Xt);
    int totW = (int)wb_elems;
    pack_w<<<(totW + 255) / 256, 256, 0, stream>>>(W, Wb, totW);
    conv_win<<<(GPIX / BNP) * (OC / BMH), 512, 0, stream>>>(Xt, Wb, out);
  } else {
    int tot = NB * OC * NPIX;
    conv_naive<<<(tot + 255) / 256, 256, 0, stream>>>(X, W, out, tot);
  }
}